// Round 8
// baseline (249.077 us; speedup 1.0000x reference)
//
#include <hip/hip_runtime.h>
#include <math.h>

#define DEV __device__ __forceinline__

// ---------------------------------------------------------------------------
// R7 = R6 + compile fix (pkrtz returns __fp16x2; bit-cast to _Float16x2).
// MFMA formulation. Features on M/K, batch on N (32 rows per wave-tile).
//   layer:  C[m=feat_out][n=batch] = A[m][k] (weights,f16) x B[k][n] (acts,f16)
// C/D layout (HW-verified m74/m101): col=lane&31, row=(reg&3)+8*(reg>>2)+4*hi.
// A/B layout (inferred): elem j <-> k = (lane>>5)*8 + j, m/n = lane&31.
// Bias folded into A at k=12 vs a constant ones-slot in B (din<=12 always).
// Inter-layer C->B transform = intra-lane pack + ONE half-wave exchange
// (2 ds_bpermute), no LDS tiles, no barriers.
// ---------------------------------------------------------------------------

typedef _Float16 f16x8 __attribute__((ext_vector_type(8)));
typedef _Float16 h2 __attribute__((ext_vector_type(2)));
typedef float f32x16 __attribute__((ext_vector_type(16)));

union BU { f16x8 v; h2 p[4]; };

DEV h2 pk2(float a, float b) {
    auto t = __builtin_amdgcn_cvt_pkrtz(a, b);  // __fp16 x2 -> bit-cast
    h2 r;
    __builtin_memcpy(&r, &t, 4);
    return r;
}

DEV h2 bperm(int addr, h2 v) {
    int x;
    __builtin_memcpy(&x, &v, 4);
    int y = __builtin_amdgcn_ds_bpermute(addr, x);
    h2 r;
    __builtin_memcpy(&r, &y, 4);
    return r;
}

// h[0..7] = relu'd (and skip-added) C regs 0..7 (features 0..15 across halves).
// Build next layer's B fragment. xaddr = (lane^32)*4.
DEV f16x8 mk_b(const float* h, bool hi, int xaddr) {
    h2 P01 = pk2(h[0], h[1]);
    h2 P23 = pk2(h[2], h[3]);
    h2 P45 = pk2(h[4], h[5]);
    h2 P67 = pk2(h[6], h[7]);
    // hi=0 lanes own feats (0,1),(2,3),(8,9),(10,11); hi=1 own (4,5),(6,7),...
    h2 sA = hi ? P01 : P45;          // what the OTHER half needs, part 1
    h2 sB = hi ? P23 : P67;          // part 2
    h2 pA = bperm(xaddr, sA);        // hi0 gets (4,5);  hi1 gets (8,9)
    h2 pB = bperm(xaddr, sB);        // hi0 gets (6,7);  hi1 gets (10,11)
    const h2 ONES = {(_Float16)1.0f, (_Float16)0.0f};  // k=12 ones slot, k=13 0
    const h2 ZER  = {(_Float16)0.0f, (_Float16)0.0f};
    BU u;
    u.p[0] = hi ? pA : P01;   // k 8hi+0,1
    u.p[1] = hi ? pB : P23;   // k 8hi+2,3
    u.p[2] = hi ? ONES : pA;  // k 8hi+4,5   (hi=1: k=12 -> 1.0 bias slot)
    u.p[3] = hi ? ZER : pB;   // k 8hi+6,7   (hi=1: k=14,15 -> 0)
    return u.v;
}

// ---- setup kernel: build per-lane A fragments (weights f16 + bias @k=12) ----
struct SrcPtrs { const float* p[28]; };

__global__ void __launch_bounds__(256)
build_a(SrcPtrs ps, f16x8* __restrict__ ws) {
    int t = blockIdx.x * blockDim.x + threadIdx.x;
    if (t >= 14 * 64) return;
    int L = t >> 6, lane = t & 63, m = lane & 31, hi = lane >> 5;
    const int DIN[14]  = {12, 12, 11, 10, 9, 8, 7, 6, 7, 8, 9, 10, 11, 12};
    const int DOUT[14] = {12, 11, 10, 9, 8, 7, 6, 7, 8, 9, 10, 11, 12, 2};
    const float* w = ps.p[2 * L];
    const float* b = ps.p[2 * L + 1];
    f16x8 f;
#pragma unroll
    for (int j = 0; j < 8; ++j) {
        int k = hi * 8 + j;
        float v = 0.0f;
        if (m < DOUT[L]) {
            if (k < DIN[L]) v = w[m * DIN[L] + k];
            else if (k == 12) v = b[m];  // bias vs ones-row
        }
        f[j] = (_Float16)v;
    }
    ws[t] = f;
}

// ---- main kernel: grid-stride over 32-row tiles ----
#define NTILES 62500   // 2,000,000 / 32

__global__ void __launch_bounds__(256)
csnet14_mfma(const float* __restrict__ x, const f16x8* __restrict__ ws,
             float* __restrict__ out, int nwaves) {
    const int tid  = blockIdx.x * blockDim.x + threadIdx.x;
    const int wave = tid >> 6;
    const int lane = threadIdx.x & 63;
    const int n    = lane & 31;        // batch col within tile
    const bool hi  = (lane >> 5) != 0; // half-wave
    const int xadr = (lane ^ 32) * 4;  // bpermute partner

    // Load all 14 A fragments (coalesced: 64 lanes x 16B = 1KB per layer).
    f16x8 A[14];
#pragma unroll
    for (int L = 0; L < 14; ++L) A[L] = ws[L * 64 + lane];

    const f32x16 zacc = {};  // persistent zero accumulator (D != C is legal)

    for (int tile = wave; tile < NTILES; tile += nwaves) {
        const int b0 = tile * 32;

        // ---- input B0: B[k][n] = x[b0+n][k]; k=12 -> 1.0; k=13..15 -> 0 ----
        const float4* xb = reinterpret_cast<const float4*>(x + (size_t)(b0 + n) * 12);
        float4 a  = xb[hi ? 2 : 0];  // feats 0-3 (hi0) / 8-11 (hi1)
        float4 bq = xb[1];           // feats 4-7 (used by hi0 only)
        const h2 ONES = {(_Float16)1.0f, (_Float16)0.0f};
        const h2 ZER  = {(_Float16)0.0f, (_Float16)0.0f};
        BU u;
        u.p[0] = pk2(a.x, a.y);
        u.p[1] = pk2(a.z, a.w);
        u.p[2] = hi ? ONES : pk2(bq.x, bq.y);
        u.p[3] = hi ? ZER  : pk2(bq.z, bq.w);
        f16x8 B = u.v;

        f32x16 C;
        float id1[8], id2[8], id3[8], id4[8], id5[8], id6[8], h[8];

        // ---- encoder: fc1..fc6 (relu, save ids) ----
#define ENC(L, IDARR)                                                        \
        C = __builtin_amdgcn_mfma_f32_32x32x16_f16(A[L], B, zacc, 0, 0, 0);  \
        _Pragma("unroll")                                                    \
        for (int r = 0; r < 8; ++r) IDARR[r] = fmaxf(C[r], 0.0f);            \
        B = mk_b(IDARR, hi, xadr);

        ENC(0, id1)
        ENC(1, id2)
        ENC(2, id3)
        ENC(3, id4)
        ENC(4, id5)
        ENC(5, id6)

        // ---- bottleneck fc7 ----
        C = __builtin_amdgcn_mfma_f32_32x32x16_f16(A[6], B, zacc, 0, 0, 0);
#pragma unroll
        for (int r = 0; r < 8; ++r) h[r] = fmaxf(C[r], 0.0f);
        B = mk_b(h, hi, xadr);

        // ---- decoder: fc8..fc13 (skip-add in f32, relu) ----
#define DEC(L, IDARR)                                                        \
        C = __builtin_amdgcn_mfma_f32_32x32x16_f16(A[L], B, zacc, 0, 0, 0);  \
        _Pragma("unroll")                                                    \
        for (int r = 0; r < 8; ++r) h[r] = fmaxf(C[r] + IDARR[r], 0.0f);     \
        B = mk_b(h, hi, xadr);

        DEC(7,  id6)
        DEC(8,  id5)
        DEC(9,  id4)
        DEC(10, id3)
        DEC(11, id2)
        DEC(12, id1)

        // ---- fc14 + softmax (logits = C rows 0,1 -> hi0 regs 0,1) ----
        C = __builtin_amdgcn_mfma_f32_32x32x16_f16(A[13], B, zacc, 0, 0, 0);
        if (!hi) {
            float l0 = C[0], l1 = C[1];
            float mx = fmaxf(l0, l1);
            float e0 = __expf(l0 - mx);
            float e1 = __expf(l1 - mx);
            float inv = __builtin_amdgcn_rcpf(e0 + e1);
            float2 o;
            o.x = e0 * inv;
            o.y = e1 * inv;
            reinterpret_cast<float2*>(out)[b0 + n] = o;
        }
    }
#undef ENC
#undef DEC
}

extern "C" void kernel_launch(void* const* d_in, const int* in_sizes, int n_in,
                              void* d_out, int out_size, void* d_ws, size_t ws_size,
                              hipStream_t stream) {
    const float* x = (const float*)d_in[0];
    float* out = (float*)d_out;
    f16x8* ws = (f16x8*)d_ws;  // needs 14*64*16 = 14,336 B

    SrcPtrs ps;
    for (int i = 0; i < 28; ++i) ps.p[i] = (const float*)d_in[1 + i];

    // Build A fragments (runs every call; d_ws is re-poisoned by the harness).
    build_a<<<4, 256, 0, stream>>>(ps, ws);

    // 1024 blocks x 4 waves = 4096 waves; ~15 tiles/wave amortizes A-load.
    const int nblocks = 1024;
    const int nwaves  = nblocks * (256 / 64);
    csnet14_mfma<<<nblocks, 256, 0, stream>>>(x, ws, out, nwaves);
}

// Round 9
// 230.885 us; speedup vs baseline: 1.0788x; 1.0788x over previous
//
#include <hip/hip_runtime.h>
#include <math.h>

#define DEV __device__ __forceinline__

// ---------------------------------------------------------------------------
// R8 = R7 + (a) TWO independent 32-row tiles per wave (interleaved dependency
// chains -> 2x latency hiding at same occupancy; R7 was latency-bound: 21%
// occupancy, MfmaUtil 13%, VALUBusy 57%, ~30% pure stall) and (b) packed-f16
// epilogue: pkrtz straight out of the MFMA, then v_pk_max_f16 / v_pk_add_f16,
// ids stored as h2 quads (halves epilogue VALU and id regs 48->24 per chain).
//
// Layout (HW-verified by R7 passing):
//   C/D: col(n)=lane&31, row f(r)=(r&3)+8*(r>>2)+4*hi  (r=0..7 used)
//   A/B: elem j <-> k=(lane>>5)*8+j, m/n=lane&31
// Bias folded into A at k=12 against a ones-slot in B (k=13..15 = 0).
// Inter-layer C->B = intra-lane pkrtz + one half-wave exchange (2 bpermute).
// ---------------------------------------------------------------------------

typedef _Float16 f16x8 __attribute__((ext_vector_type(8)));
typedef _Float16 h2 __attribute__((ext_vector_type(2)));
typedef float f32x16 __attribute__((ext_vector_type(16)));

union BU { f16x8 v; h2 p[4]; };

DEV h2 pk2(float a, float b) {
    auto t = __builtin_amdgcn_cvt_pkrtz(a, b);  // __fp16x2 -> bit-cast
    h2 r;
    __builtin_memcpy(&r, &t, 4);
    return r;
}

DEV h2 bperm(int addr, h2 v) {
    int x;
    __builtin_memcpy(&x, &v, 4);
    int y = __builtin_amdgcn_ds_bpermute(addr, x);
    h2 r;
    __builtin_memcpy(&r, &y, 4);
    return r;
}

DEV h2 h2max0(h2 v) {
    const h2 Z = {(_Float16)0.0f, (_Float16)0.0f};
    return __builtin_elementwise_max(v, Z);  // v_pk_max_f16
}

// Pack MFMA C regs 0..7 into owning-quad layout:
// q0=feats(4hi+0,1) q1=(4hi+2,3) q2=(8+4hi,9+4hi) q3=(10+4hi,11+4hi)
DEV void pack4(const f32x16& C, h2 q[4]) {
    q[0] = pk2(C[0], C[1]);
    q[1] = pk2(C[2], C[3]);
    q[2] = pk2(C[4], C[5]);
    q[3] = pk2(C[6], C[7]);
}

// Build next layer's B fragment from owning quads. xaddr = (lane^32)*4.
// hi=0 needs k=0..7: own q0,q1 + partner's (4,5),(6,7) [= hi1's q0,q1]
// hi=1 needs k=8..15: partner's (8,9),(10,11) [= hi0's q2,q3] + bias/zero
DEV f16x8 mk_b(const h2 q[4], bool hi, int xaddr) {
    h2 sA = hi ? q[0] : q[2];
    h2 sB = hi ? q[1] : q[3];
    h2 pA = bperm(xaddr, sA);  // hi0 <- (4,5);  hi1 <- (8,9)
    h2 pB = bperm(xaddr, sB);  // hi0 <- (6,7);  hi1 <- (10,11)
    const h2 ONES = {(_Float16)1.0f, (_Float16)0.0f};  // k=12 bias slot
    const h2 ZER  = {(_Float16)0.0f, (_Float16)0.0f};
    BU u;
    u.p[0] = hi ? pA : q[0];
    u.p[1] = hi ? pB : q[1];
    u.p[2] = hi ? ONES : pA;
    u.p[3] = hi ? ZER  : pB;
    return u.v;
}

// ---- setup kernel: per-lane A fragments (weights f16, bias @ k=12) ----
struct SrcPtrs { const float* p[28]; };

__global__ void __launch_bounds__(256)
build_a(SrcPtrs ps, f16x8* __restrict__ ws) {
    int t = blockIdx.x * blockDim.x + threadIdx.x;
    if (t >= 14 * 64) return;
    int L = t >> 6, lane = t & 63, m = lane & 31, hi = lane >> 5;
    const int DIN[14]  = {12, 12, 11, 10, 9, 8, 7, 6, 7, 8, 9, 10, 11, 12};
    const int DOUT[14] = {12, 11, 10, 9, 8, 7, 6, 7, 8, 9, 10, 11, 12, 2};
    const float* w = ps.p[2 * L];
    const float* b = ps.p[2 * L + 1];
    f16x8 f;
#pragma unroll
    for (int j = 0; j < 8; ++j) {
        int k = hi * 8 + j;
        float v = 0.0f;
        if (m < DOUT[L]) {
            if (k < DIN[L]) v = w[m * DIN[L] + k];
            else if (k == 12) v = b[m];
        }
        f[j] = (_Float16)v;
    }
    ws[t] = f;
}

// ---- main kernel: 2 tiles (64 rows) per wave-iteration ----
#define PAIRS 31250   // 2,000,000 rows / 64

__global__ void __launch_bounds__(256)
csnet14_mfma(const float* __restrict__ x, const f16x8* __restrict__ ws,
             float* __restrict__ out, int nwaves) {
    const int tid  = blockIdx.x * blockDim.x + threadIdx.x;
    const int wave = tid >> 6;
    const int lane = threadIdx.x & 63;
    const int n    = lane & 31;
    const bool hi  = (lane >> 5) != 0;
    const int xadr = (lane ^ 32) * 4;

    f16x8 A[14];
#pragma unroll
    for (int L = 0; L < 14; ++L) A[L] = ws[L * 64 + lane];

    const f32x16 zacc = {};

    for (int p = wave; p < PAIRS; p += nwaves) {
        const int base = p * 64;  // chain 0: rows base..base+31; chain 1: +32

        // ---- input B for both chains ----
        f16x8 B[2];
#pragma unroll
        for (int c = 0; c < 2; ++c) {
            const float4* xb =
                reinterpret_cast<const float4*>(x + (size_t)(base + 32 * c + n) * 12);
            float4 a  = xb[hi ? 2 : 0];
            float4 bq = xb[1];
            const h2 ONES = {(_Float16)1.0f, (_Float16)0.0f};
            const h2 ZER  = {(_Float16)0.0f, (_Float16)0.0f};
            BU u;
            u.p[0] = pk2(a.x, a.y);
            u.p[1] = pk2(a.z, a.w);
            u.p[2] = hi ? ONES : pk2(bq.x, bq.y);
            u.p[3] = hi ? ZER  : pk2(bq.z, bq.w);
            B[c] = u.v;
        }

        f32x16 C[2];
        h2 ids[6][2][4];  // packed post-relu identities
        h2 q[2][4];

        // ---- encoder fc1..fc6 ----
#define ENC(L)                                                               \
        _Pragma("unroll")                                                    \
        for (int c = 0; c < 2; ++c)                                          \
            C[c] = __builtin_amdgcn_mfma_f32_32x32x16_f16(A[L], B[c], zacc, 0, 0, 0); \
        _Pragma("unroll")                                                    \
        for (int c = 0; c < 2; ++c) {                                        \
            pack4(C[c], q[c]);                                               \
            _Pragma("unroll")                                                \
            for (int j = 0; j < 4; ++j) {                                    \
                q[c][j] = h2max0(q[c][j]);                                   \
                ids[L][c][j] = q[c][j];                                      \
            }                                                                \
            B[c] = mk_b(q[c], hi, xadr);                                     \
        }

        ENC(0) ENC(1) ENC(2) ENC(3) ENC(4) ENC(5)

        // ---- bottleneck fc7 (relu only) ----
#pragma unroll
        for (int c = 0; c < 2; ++c)
            C[c] = __builtin_amdgcn_mfma_f32_32x32x16_f16(A[6], B[c], zacc, 0, 0, 0);
#pragma unroll
        for (int c = 0; c < 2; ++c) {
            pack4(C[c], q[c]);
#pragma unroll
            for (int j = 0; j < 4; ++j) q[c][j] = h2max0(q[c][j]);
            B[c] = mk_b(q[c], hi, xadr);
        }

        // ---- decoder fc8..fc13 (packed skip-add, then relu) ----
#define DEC(L, IDL)                                                          \
        _Pragma("unroll")                                                    \
        for (int c = 0; c < 2; ++c)                                          \
            C[c] = __builtin_amdgcn_mfma_f32_32x32x16_f16(A[L], B[c], zacc, 0, 0, 0); \
        _Pragma("unroll")                                                    \
        for (int c = 0; c < 2; ++c) {                                        \
            pack4(C[c], q[c]);                                               \
            _Pragma("unroll")                                                \
            for (int j = 0; j < 4; ++j)                                      \
                q[c][j] = h2max0(q[c][j] + ids[IDL][c][j]);                  \
            B[c] = mk_b(q[c], hi, xadr);                                     \
        }

        DEC(7, 5) DEC(8, 4) DEC(9, 3) DEC(10, 2) DEC(11, 1) DEC(12, 0)

        // ---- fc14 + softmax (f32 logits: hi0 regs 0,1) ----
#pragma unroll
        for (int c = 0; c < 2; ++c)
            C[c] = __builtin_amdgcn_mfma_f32_32x32x16_f16(A[13], B[c], zacc, 0, 0, 0);
        if (!hi) {
#pragma unroll
            for (int c = 0; c < 2; ++c) {
                float l0 = C[c][0], l1 = C[c][1];
                float mx = fmaxf(l0, l1);
                float e0 = __expf(l0 - mx);
                float e1 = __expf(l1 - mx);
                float inv = __builtin_amdgcn_rcpf(e0 + e1);
                float2 o;
                o.x = e0 * inv;
                o.y = e1 * inv;
                reinterpret_cast<float2*>(out)[base + 32 * c + n] = o;
            }
        }
#undef ENC
#undef DEC
    }
}

extern "C" void kernel_launch(void* const* d_in, const int* in_sizes, int n_in,
                              void* d_out, int out_size, void* d_ws, size_t ws_size,
                              hipStream_t stream) {
    const float* x = (const float*)d_in[0];
    float* out = (float*)d_out;
    f16x8* ws = (f16x8*)d_ws;  // 14*64*16 = 14,336 B

    SrcPtrs ps;
    for (int i = 0; i < 28; ++i) ps.p[i] = (const float*)d_in[1 + i];

    build_a<<<4, 256, 0, stream>>>(ps, ws);

    const int nblocks = 1024;
    const int nwaves  = nblocks * (256 / 64);
    csnet14_mfma<<<nblocks, 256, 0, stream>>>(x, ws, out, nwaves);
}